// Round 11
// baseline (687.709 us; speedup 1.0000x reference)
//
#include <hip/hip_runtime.h>
#include <hip/hip_bf16.h>

#define NN 20000
#define DD 512
#define EE 150000
#define NH 2560  // stacked GEMM width: 4*512 (W_i) + 512 (Wl_top)

typedef __attribute__((ext_vector_type(8))) short short8;
typedef __attribute__((ext_vector_type(4))) float floatx4;

static __device__ __forceinline__ float bfbits2f(unsigned short u) {
    unsigned int x = ((unsigned int)u) << 16;
    return __uint_as_float(x);
}

#define GLOAD_LDS16(g, l)                                                        \
    __builtin_amdgcn_global_load_lds((const __attribute__((address_space(1))) void*)(g), \
                                     (__attribute__((address_space(3))) void*)(l), 16, 0, 0)

// ---------------- convert fp32 -> bf16 ----------------
__global__ __launch_bounds__(256) void k_convert_bf16(const float* __restrict__ in,
                                                      __hip_bfloat16* __restrict__ out, int n4) {
    int i = blockIdx.x * blockDim.x + threadIdx.x;
    if (i >= n4) return;
    float4 v = ((const float4*)in)[i];
    union { __hip_bfloat16 b[4]; ushort4 u; } cv;
    cv.b[0] = __float2bfloat16(v.x);
    cv.b[1] = __float2bfloat16(v.y);
    cv.b[2] = __float2bfloat16(v.z);
    cv.b[3] = __float2bfloat16(v.w);
    *(ushort4*)(out + 4l * i) = cv.u;
}

// ---------------- 512x512 transpose + convert to bf16 ----------------
__global__ __launch_bounds__(1024) void k_transpose_bf16(const float* __restrict__ in,
                                                         __hip_bfloat16* __restrict__ out) {
    __shared__ float tile[32][33];
    int bx = blockIdx.x * 32;
    int by = blockIdx.y * 32;
    int tx = threadIdx.x, ty = threadIdx.y;
    tile[ty][tx] = in[(by + ty) * 512 + bx + tx];
    __syncthreads();
    out[(bx + ty) * 512 + by + tx] = __float2bfloat16(tile[tx][ty]);
}

// ---------------- pack al/ar: alr[rel][0:512]=al_rel, [512:1024]=ar_rel ----------------
__global__ __launch_bounds__(256)
void k_pack_alr(const float* __restrict__ al0, const float* __restrict__ al1,
                const float* __restrict__ al2, const float* __restrict__ al3,
                const float* __restrict__ ar0, const float* __restrict__ ar1,
                const float* __restrict__ ar2, const float* __restrict__ ar3,
                float* __restrict__ alr) {
    int c = blockIdx.x * 256 + threadIdx.x;  // 0..511
    if (c >= 512) return;
    alr[0 * 1024 + c] = al0[c];
    alr[1 * 1024 + c] = al1[c];
    alr[2 * 1024 + c] = al2[c];
    alr[3 * 1024 + c] = al3[c];
    alr[0 * 1024 + 512 + c] = ar0[c];
    alr[1 * 1024 + 512 + c] = ar1[c];
    alr[2 * 1024 + 512 + c] = ar2[c];
    alr[3 * 1024 + 512 + c] = ar3[c];
}

// ---------------- MEGA GEMM: 128x128, BK=64, XCD swizzle + fused el/er ----------
// ctile<16 (relation cols): epilogue dots the 64 wave-cols against al/ar,
// shfl-reduces over l15 and atomicAdds per-row partials into el4/er4
// (el4/er4 zero-initialized each call; saves the 102MB h_all re-read).
__global__ __launch_bounds__(256)
void k_gemm128(const __hip_bfloat16* __restrict__ A, const __hip_bfloat16* __restrict__ Bt,
               __hip_bfloat16* __restrict__ Cb, const float* __restrict__ alr,
               float* __restrict__ el4, float* __restrict__ er4, int c_ld, int M, int CT) {
    const int RT = (M + 127) >> 7;
    const int xcd = blockIdx.x & 7;
    const int k_ = blockIdx.x >> 3;
    const int ctile = k_ % CT;
    const int rtile = (k_ / CT) * 8 + xcd;
    if (rtile >= RT) return;

    __shared__ __hip_bfloat16 As[128 * 64];
    __shared__ __hip_bfloat16 Bs[128 * 64];
    const int tid = threadIdx.x;
    const int lane = tid & 63;
    const int wave = tid >> 6;
    const int row0 = rtile * 128;
    const int col0 = ctile * 128;
    const int wm = (wave >> 1) * 64;
    const int wn = (wave & 1) * 64;
    const int q8 = lane >> 4;
    const int l15 = lane & 15;

    int ar_ = row0 + (tid & 127);
    if (ar_ >= M) ar_ = M - 1;
    const __hip_bfloat16* aptr = A + (size_t)ar_ * DD + (tid >> 7) * 8;
    const __hip_bfloat16* bptr = Bt + (size_t)(col0 + (tid & 127)) * DD + (tid >> 7) * 8;
    __hip_bfloat16* alds = As + (size_t)tid * 8;
    __hip_bfloat16* blds = Bs + (size_t)tid * 8;

    floatx4 acc[4][4];
#pragma unroll
    for (int a = 0; a < 4; a++)
#pragma unroll
        for (int b = 0; b < 4; b++) acc[a][b] = (floatx4){0.f, 0.f, 0.f, 0.f};

    for (int k0 = 0; k0 < DD; k0 += 64) {
        __syncthreads();
#pragma unroll
        for (int j = 0; j < 4; j++) {
            GLOAD_LDS16(aptr + k0 + j * 16, alds + (size_t)j * 256 * 8);
            GLOAD_LDS16(bptr + k0 + j * 16, blds + (size_t)j * 256 * 8);
        }
        __syncthreads();
#pragma unroll
        for (int kk = 0; kk < 2; kk++) {
            short8 af[4], bf[4];
#pragma unroll
            for (int mi = 0; mi < 4; mi++)
                af[mi] =
                    *(const short8*)(As + ((size_t)(kk * 4 + q8) * 128 + wm + mi * 16 + l15) * 8);
#pragma unroll
            for (int ni = 0; ni < 4; ni++)
                bf[ni] =
                    *(const short8*)(Bs + ((size_t)(kk * 4 + q8) * 128 + wn + ni * 16 + l15) * 8);
#pragma unroll
            for (int mi = 0; mi < 4; mi++)
#pragma unroll
                for (int ni = 0; ni < 4; ni++)
                    acc[mi][ni] = __builtin_amdgcn_mfma_f32_16x16x32_bf16(af[mi], bf[ni],
                                                                          acc[mi][ni], 0, 0, 0);
        }
    }

#pragma unroll
    for (int mi = 0; mi < 4; mi++)
#pragma unroll
        for (int ni = 0; ni < 4; ni++)
#pragma unroll
            for (int r = 0; r < 4; r++) {
                int grow = row0 + wm + mi * 16 + q8 * 4 + r;
                int gcol = col0 + wn + ni * 16 + l15;
                if (grow < M) Cb[(size_t)grow * c_ld + gcol] = __float2bfloat16(acc[mi][ni][r]);
            }

    // fused el/er partials for relation columns
    if (ctile < 16) {
        const int rel = ctile >> 2;
        const int cb = (ctile & 3) * 128 + wn;
        float alv[4], arv[4];
#pragma unroll
        for (int ni = 0; ni < 4; ni++) {
            alv[ni] = alr[rel * 1024 + cb + ni * 16 + l15];
            arv[ni] = alr[rel * 1024 + 512 + cb + ni * 16 + l15];
        }
#pragma unroll
        for (int mi = 0; mi < 4; mi++)
#pragma unroll
            for (int r = 0; r < 4; r++) {
                float sl = acc[mi][0][r] * alv[0] + acc[mi][1][r] * alv[1] +
                           acc[mi][2][r] * alv[2] + acc[mi][3][r] * alv[3];
                float sr = acc[mi][0][r] * arv[0] + acc[mi][1][r] * arv[1] +
                           acc[mi][2][r] * arv[2] + acc[mi][3][r] * arv[3];
#pragma unroll
                for (int off = 1; off < 16; off <<= 1) {
                    sl += __shfl_xor(sl, off);
                    sr += __shfl_xor(sr, off);
                }
                if (l15 == 0) {
                    int grow = row0 + wm + mi * 16 + q8 * 4 + r;
                    if (grow < M) {
                        atomicAdd(&el4[rel * NN + grow], sl);
                        atomicAdd(&er4[rel * NN + grow], sr);
                    }
                }
            }
    }
}

// ---------------- CHAIN GEMM with fused t-propagation (R10-proven) ----------------
__global__ __launch_bounds__(256)
void k_chain(const __hip_bfloat16* __restrict__ A, const __hip_bfloat16* __restrict__ Bt,
             const __hip_bfloat16* __restrict__ xwl, const __hip_bfloat16* __restrict__ gnext,
             __hip_bfloat16* __restrict__ t_next, float* __restrict__ outf, int M) {
    const int CT = 4;
    const int RT = (M + 63) >> 6;
    const int xcd = blockIdx.x & 7;
    const int k_ = blockIdx.x >> 3;
    const int ctile = k_ % CT;
    const int rtile = (k_ / CT) * 8 + xcd;
    if (rtile >= RT) return;

    __shared__ __hip_bfloat16 As[64 * 64];
    __shared__ __hip_bfloat16 Bs[128 * 64];
    const int tid = threadIdx.x;
    const int lane = tid & 63;
    const int wave = tid >> 6;
    const int row0 = rtile * 64;
    const int col0 = ctile * 128;
    const int wm = (wave >> 1) * 32;
    const int wn = (wave & 1) * 64;
    const int q8 = lane >> 4;
    const int l15 = lane & 15;

    int ar_ = row0 + (tid & 63);
    if (ar_ >= M) ar_ = M - 1;
    const __hip_bfloat16* aptr = A + (size_t)ar_ * DD + (tid >> 6) * 8;
    __hip_bfloat16* alds = As + (size_t)tid * 8;
    const __hip_bfloat16* bptr = Bt + (size_t)(col0 + (tid & 127)) * DD + (tid >> 7) * 8;
    __hip_bfloat16* blds = Bs + (size_t)tid * 8;

    floatx4 acc[2][4];
#pragma unroll
    for (int a = 0; a < 2; a++)
#pragma unroll
        for (int b = 0; b < 4; b++) acc[a][b] = (floatx4){0.f, 0.f, 0.f, 0.f};

    for (int k0 = 0; k0 < DD; k0 += 64) {
        __syncthreads();
        GLOAD_LDS16(aptr + k0, alds);
        GLOAD_LDS16(aptr + k0 + 32, alds + 256 * 8);
#pragma unroll
        for (int j = 0; j < 4; j++)
            GLOAD_LDS16(bptr + k0 + j * 16, blds + (size_t)j * 256 * 8);
        __syncthreads();
#pragma unroll
        for (int kk = 0; kk < 2; kk++) {
            short8 af[2], bf[4];
#pragma unroll
            for (int mi = 0; mi < 2; mi++)
                af[mi] =
                    *(const short8*)(As + ((size_t)(kk * 4 + q8) * 64 + wm + mi * 16 + l15) * 8);
#pragma unroll
            for (int ni = 0; ni < 4; ni++)
                bf[ni] =
                    *(const short8*)(Bs + ((size_t)(kk * 4 + q8) * 128 + wn + ni * 16 + l15) * 8);
#pragma unroll
            for (int mi = 0; mi < 2; mi++)
#pragma unroll
                for (int ni = 0; ni < 4; ni++)
                    acc[mi][ni] = __builtin_amdgcn_mfma_f32_16x16x32_bf16(af[mi], bf[ni],
                                                                          acc[mi][ni], 0, 0, 0);
        }
    }

#pragma unroll
    for (int mi = 0; mi < 2; mi++)
#pragma unroll
        for (int ni = 0; ni < 4; ni++)
#pragma unroll
            for (int r = 0; r < 4; r++) {
                int grow = row0 + wm + mi * 16 + q8 * 4 + r;
                int gcol = col0 + wn + ni * 16 + l15;
                if (grow < M) {
                    float v = acc[mi][ni][r];
                    v += bfbits2f(*(const unsigned short*)(xwl + (size_t)grow * NH + 2048 + gcol));
                    v = v > 0.f ? v : 0.f;  // v = out_i
                    size_t idx = (size_t)grow * DD + gcol;
                    if (t_next) {
                        v += bfbits2f(*(const unsigned short*)(gnext + idx));
                        t_next[idx] = __float2bfloat16(v);
                    } else {
                        outf[idx] = v;
                    }
                }
            }
}

// ---------------- CSR build (batched over 4 relations) ----------------
__global__ void k_zero_i32(int* p, int n) {
    int i = blockIdx.x * blockDim.x + threadIdx.x;
    if (i < n) p[i] = 0;
}

__global__ void k_count4(const int* __restrict__ e0, const int* __restrict__ e1,
                         const int* __restrict__ e2, const int* __restrict__ e3,
                         int* __restrict__ deg4) {
    int g = blockIdx.x * blockDim.x + threadIdx.x;
    if (g >= 4 * EE) return;
    int rel = g / EE;
    int e = g - rel * EE;
    const int* ed = rel == 0 ? e0 : rel == 1 ? e1 : rel == 2 ? e2 : e3;
    atomicAdd(&deg4[rel * NN + ed[EE + e]], 1);
}

__global__ __launch_bounds__(1024)
void k_scan4(const int* __restrict__ deg4, int* __restrict__ rp4, int* __restrict__ cur4) {
    const int rel = blockIdx.x;
    const int* deg = deg4 + rel * NN;
    int* row_ptr = rp4 + rel * (NN + 1);
    int* cursor = cur4 + rel * NN;
    __shared__ int sm[1024];
    int t = threadIdx.x;
    const int CH = 20;
    int begin = t * CH;
    int end = begin + CH;
    if (end > NN) end = NN;
    int s = 0;
    if (begin < NN)
        for (int i = begin; i < end; i++) s += deg[i];
    sm[t] = s;
    __syncthreads();
    for (int off = 1; off < 1024; off <<= 1) {
        int v = (t >= off) ? sm[t - off] : 0;
        __syncthreads();
        sm[t] += v;
        __syncthreads();
    }
    int run = sm[t] - s;
    if (begin < NN) {
        for (int i = begin; i < end; i++) {
            row_ptr[i] = run;
            cursor[i] = run;
            run += deg[i];
        }
        if (end == NN) row_ptr[NN] = run;
    }
}

__global__ void k_scatter4(const int* __restrict__ e0, const int* __restrict__ e1,
                           const int* __restrict__ e2, const int* __restrict__ e3,
                           int* __restrict__ cur4, int* __restrict__ csr4) {
    int g = blockIdx.x * blockDim.x + threadIdx.x;
    if (g >= 4 * EE) return;
    int rel = g / EE;
    int e = g - rel * EE;
    const int* ed = rel == 0 ? e0 : rel == 1 ? e1 : rel == 2 ? e2 : e3;
    int dst = ed[EE + e];
    int pos = atomicAdd(&cur4[rel * NN + dst], 1);
    csr4[rel * EE + pos] = ed[e];
}

// ---------------- BATCHED aggregate, 2 waves per dst (256 cols each) ----------
// gat4[rel][dst][:] = bias + sum_j alpha_j h_rel[src_j][:].
// 160K waves total: 2x gather streams vs R10 for latency hiding.
__global__ __launch_bounds__(256)
void k_agg4(const int* __restrict__ rp4, const int* __restrict__ csr4,
            const float* __restrict__ el4, const float* __restrict__ er4,
            const __hip_bfloat16* __restrict__ h_all, const float* __restrict__ bias,
            __hip_bfloat16* __restrict__ gat4, float* __restrict__ alpha8) {
    const int rel = blockIdx.y;
    const int* row_ptr = rp4 + rel * (NN + 1);
    const int* csr_src = csr4 + (size_t)rel * EE;
    const float* el = el4 + rel * NN;
    const float* er = er4 + rel * NN;
    const __hip_bfloat16* h = h_all + (size_t)rel * 512;

    int wglob = blockIdx.x * 4 + (threadIdx.x >> 6);
    int d = wglob >> 1;
    int half = wglob & 1;
    int lane = threadIdx.x & 63;
    if (d >= NN) return;
    float* alpha_tmp = alpha8 + (size_t)(rel * 2 + half) * EE;
    int s0 = row_ptr[d], s1 = row_ptr[d + 1];
    int deg = s1 - s0;
    int base = half * 256 + lane * 4;
    float acc[4] = {0.f, 0.f, 0.f, 0.f};

    if (deg <= 64) {
        int sv = 0;
        float av = 0.f;
        if (lane < deg) sv = csr_src[s0 + lane];
        float erd = er[d];
        float v = -1e30f;
        if (lane < deg) {
            float e = el[sv] + erd;
            v = e >= 0.f ? e : 0.2f * e;
        }
        float m = v;
#pragma unroll
        for (int off = 32; off > 0; off >>= 1) m = fmaxf(m, __shfl_xor(m, off));
        float wgt = (lane < deg) ? __expf(v - m) : 0.f;
        float s = wgt;
#pragma unroll
        for (int off = 32; off > 0; off >>= 1) s += __shfl_xor(s, off);
        av = wgt / s;
        int t = 0;
        for (; t + 3 < deg; t += 4) {
            int sA = __shfl(sv, t), sB = __shfl(sv, t + 1);
            int sC = __shfl(sv, t + 2), sD = __shfl(sv, t + 3);
            float aA = __shfl(av, t), aB = __shfl(av, t + 1);
            float aC = __shfl(av, t + 2), aD = __shfl(av, t + 3);
            uint2 hv0 = *(const uint2*)(h + (size_t)sA * NH + base);
            uint2 hv1 = *(const uint2*)(h + (size_t)sB * NH + base);
            uint2 hv2 = *(const uint2*)(h + (size_t)sC * NH + base);
            uint2 hv3 = *(const uint2*)(h + (size_t)sD * NH + base);
            const unsigned short* h0 = (const unsigned short*)&hv0;
            const unsigned short* h1 = (const unsigned short*)&hv1;
            const unsigned short* h2 = (const unsigned short*)&hv2;
            const unsigned short* h3 = (const unsigned short*)&hv3;
#pragma unroll
            for (int k = 0; k < 4; k++)
                acc[k] += aA * bfbits2f(h0[k]) + aB * bfbits2f(h1[k]) + aC * bfbits2f(h2[k]) +
                          aD * bfbits2f(h3[k]);
        }
        for (; t < deg; t++) {
            int sA = __shfl(sv, t);
            float aA = __shfl(av, t);
            uint2 hv0 = *(const uint2*)(h + (size_t)sA * NH + base);
            const unsigned short* h0 = (const unsigned short*)&hv0;
#pragma unroll
            for (int k = 0; k < 4; k++) acc[k] += aA * bfbits2f(h0[k]);
        }
    } else {
        float erd = er[d];
        float m = -1e30f;
        for (int j = s0 + lane; j < s1; j += 64) {
            float e = el[csr_src[j]] + erd;
            e = e >= 0.f ? e : 0.2f * e;
            alpha_tmp[j] = e;
            m = fmaxf(m, e);
        }
#pragma unroll
        for (int off = 32; off > 0; off >>= 1) m = fmaxf(m, __shfl_xor(m, off));
        float s = 0.f;
        for (int j = s0 + lane; j < s1; j += 64) {
            float wv = __expf(alpha_tmp[j] - m);
            alpha_tmp[j] = wv;
            s += wv;
        }
#pragma unroll
        for (int off = 32; off > 0; off >>= 1) s += __shfl_xor(s, off);
        float inv = 1.f / s;
        for (int j0 = 0; j0 < deg; j0 += 64) {
            int cnt = deg - j0;
            if (cnt > 64) cnt = 64;
            int sv = 0;
            float av = 0.f;
            if (lane < cnt) {
                sv = csr_src[s0 + j0 + lane];
                av = alpha_tmp[s0 + j0 + lane] * inv;
            }
            for (int t = 0; t < cnt; t++) {
                int sA = __shfl(sv, t);
                float aA = __shfl(av, t);
                uint2 hv0 = *(const uint2*)(h + (size_t)sA * NH + base);
                const unsigned short* h0 = (const unsigned short*)&hv0;
#pragma unroll
                for (int k = 0; k < 4; k++) acc[k] += aA * bfbits2f(h0[k]);
            }
        }
    }

    float4 b0 = *(const float4*)(bias + base);
    acc[0] += b0.x;
    acc[1] += b0.y;
    acc[2] += b0.z;
    acc[3] += b0.w;
    union { __hip_bfloat16 b[4]; uint2 u; } cv;
#pragma unroll
    for (int k = 0; k < 4; k++) cv.b[k] = __float2bfloat16(acc[k]);
    *(uint2*)(gat4 + (size_t)rel * NN * DD + (size_t)d * DD + base) = cv.u;
}

extern "C" void kernel_launch(void* const* d_in, const int* in_sizes, int n_in,
                              void* d_out, int out_size, void* d_ws, size_t ws_size,
                              hipStream_t stream) {
    const float* x = (const float*)d_in[0];
    const int* edges[4] = {(const int*)d_in[1], (const int*)d_in[5], (const int*)d_in[9],
                           (const int*)d_in[13]};
    const float* W[4] = {(const float*)d_in[2], (const float*)d_in[6], (const float*)d_in[10],
                         (const float*)d_in[14]};
    const float* al[4] = {(const float*)d_in[3], (const float*)d_in[7], (const float*)d_in[11],
                          (const float*)d_in[15]};
    const float* ar[4] = {(const float*)d_in[4], (const float*)d_in[8], (const float*)d_in[12],
                          (const float*)d_in[16]};
    const float* Wl = (const float*)d_in[17];
    const float* bias = (const float*)d_in[18];
    float* out = (float*)d_out;

    char* w = (char*)d_ws;
    auto alloc = [&](size_t bytes) {
        char* p = w;
        w += (bytes + 255) & ~(size_t)255;
        return p;
    };
    __hip_bfloat16* x_bf = (__hip_bfloat16*)alloc((size_t)NN * DD * 2);
    __hip_bfloat16* h_all = (__hip_bfloat16*)alloc((size_t)NN * NH * 2);   // [h0..h3|xwl]
    __hip_bfloat16* gat4 = (__hip_bfloat16*)alloc((size_t)4 * NN * DD * 2);
    __hip_bfloat16* t_A = (__hip_bfloat16*)alloc((size_t)NN * DD * 2);
    __hip_bfloat16* t_B = (__hip_bfloat16*)alloc((size_t)NN * DD * 2);
    __hip_bfloat16* Bt_all = (__hip_bfloat16*)alloc((size_t)NH * DD * 2);  // [W0..W3,WlTop]^T
    __hip_bfloat16* WlTb = (__hip_bfloat16*)alloc((size_t)DD * DD * 2);
    float* alr = (float*)alloc((size_t)4 * 1024 * 4);
    // deg4/el4/er4 contiguous so one zero-kernel covers them (el/er needed for atomics)
    int* deg4 = (int*)alloc((size_t)4 * NN * 4);
    float* el4 = (float*)alloc((size_t)4 * NN * 4);
    float* er4 = (float*)alloc((size_t)4 * NN * 4);
    int* rp4 = (int*)alloc((size_t)4 * (NN + 1) * 4);
    int* cur4 = (int*)alloc((size_t)4 * NN * 4);
    int* csr4 = (int*)alloc((size_t)4 * EE * 4);
    float* alpha8 = (float*)alloc((size_t)8 * EE * 4);

    // preprocessing
    k_convert_bf16<<<(NN * DD / 4 + 255) / 256, 256, 0, stream>>>(x, x_bf, NN * DD / 4);
    dim3 tb(32, 32), tg(16, 16);
    for (int i = 0; i < 4; i++)
        k_transpose_bf16<<<tg, tb, 0, stream>>>(W[i], Bt_all + (size_t)i * DD * DD);
    k_transpose_bf16<<<tg, tb, 0, stream>>>(Wl, Bt_all + (size_t)4 * DD * DD);
    k_transpose_bf16<<<tg, tb, 0, stream>>>(Wl + DD * DD, WlTb);
    k_pack_alr<<<2, 256, 0, stream>>>(al[0], al[1], al[2], al[3], ar[0], ar[1], ar[2], ar[3], alr);

    // zero deg4 + el4 + er4 (span includes alignment padding, all 4-byte words)
    int zspan = (int)(((char*)er4 - (char*)deg4) / 4) + 4 * NN;
    k_zero_i32<<<(zspan + 255) / 256, 256, 0, stream>>>(deg4, zspan);
    k_count4<<<(4 * EE + 255) / 256, 256, 0, stream>>>(edges[0], edges[1], edges[2], edges[3], deg4);
    k_scan4<<<4, 1024, 0, stream>>>(deg4, rp4, cur4);
    k_scatter4<<<(4 * EE + 255) / 256, 256, 0, stream>>>(edges[0], edges[1], edges[2], edges[3],
                                                         cur4, csr4);

    // MEGA-GEMM + fused el/er: h_all = x @ [W0..W3|Wl_top]
    const int RT128p8 = (((NN + 127) / 128 + 7) / 8) * 8;  // 160
    k_gemm128<<<RT128p8 * 20, 256, 0, stream>>>(x_bf, Bt_all, h_all, alr, el4, er4, NH, NN, 20);

    // batched aggregate (+bias), 2 waves/dst
    dim3 gagg((NN * 2 * 64 + 255) / 256, 4);
    k_agg4<<<gagg, 256, 0, stream>>>(rp4, csr4, el4, er4, h_all, bias, gat4, alpha8);

    // serial chain: t_{i+1} = relu(t_i @ Wl_bot + xwl) + gat4[i+1]; last writes fp32 out
    const int RT64p8 = (((NN + 63) / 64 + 7) / 8) * 8;  // 320
    const int NB = RT64p8 * 4;
    k_chain<<<NB, 256, 0, stream>>>(gat4, WlTb, h_all, gat4 + (size_t)1 * NN * DD, t_A, nullptr,
                                    NN);
    k_chain<<<NB, 256, 0, stream>>>(t_A, WlTb, h_all, gat4 + (size_t)2 * NN * DD, t_B, nullptr,
                                    NN);
    k_chain<<<NB, 256, 0, stream>>>(t_B, WlTb, h_all, gat4 + (size_t)3 * NN * DD, t_A, nullptr,
                                    NN);
    k_chain<<<NB, 256, 0, stream>>>(t_A, WlTb, h_all, nullptr, nullptr, out, NN);
}

// Round 12
// 660.907 us; speedup vs baseline: 1.0406x; 1.0406x over previous
//
#include <hip/hip_runtime.h>
#include <hip/hip_bf16.h>

#define NN 20000
#define DD 512
#define EE 150000
#define NH 2560  // stacked GEMM width: 4*512 (W_i) + 512 (Wl_top)

typedef __attribute__((ext_vector_type(8))) short short8;
typedef __attribute__((ext_vector_type(4))) float floatx4;

static __device__ __forceinline__ float bfbits2f(unsigned short u) {
    unsigned int x = ((unsigned int)u) << 16;
    return __uint_as_float(x);
}

#define GLOAD_LDS16(g, l)                                                        \
    __builtin_amdgcn_global_load_lds((const __attribute__((address_space(1))) void*)(g), \
                                     (__attribute__((address_space(3))) void*)(l), 16, 0, 0)

// ---------------- fused preprocessing: convert x, zero deg4, wal8 ----------------
// blocks [0,10000): x fp32 -> bf16 (4 elems/thread)
// blocks [10000,10313): zero deg4 (4*NN ints)
// blocks [10313,10377): wal8[v][k] = sum_n W[rel][k][n]*vec[n]
//   v = (blk-10313)>>3 (0..7: al0..3, ar0..3), kgroup = (blk-10313)&7
#define PRE_CONV 10000
#define PRE_ZERO 313
#define PRE_WAL 64
__global__ __launch_bounds__(256)
void k_preproc(const float* __restrict__ x, __hip_bfloat16* __restrict__ x_bf,
               int* __restrict__ deg4,
               const float* __restrict__ W0, const float* __restrict__ W1,
               const float* __restrict__ W2, const float* __restrict__ W3,
               const float* __restrict__ al0, const float* __restrict__ al1,
               const float* __restrict__ al2, const float* __restrict__ al3,
               const float* __restrict__ ar0, const float* __restrict__ ar1,
               const float* __restrict__ ar2, const float* __restrict__ ar3,
               float* __restrict__ wal8) {
    int b = blockIdx.x;
    int tid = threadIdx.x;
    if (b < PRE_CONV) {
        int i = b * 256 + tid;  // 4 elems each, exact (NN*DD/4 = 2,560,000)
        float4 v = ((const float4*)x)[i];
        union { __hip_bfloat16 bb[4]; ushort4 u; } cv;
        cv.bb[0] = __float2bfloat16(v.x);
        cv.bb[1] = __float2bfloat16(v.y);
        cv.bb[2] = __float2bfloat16(v.z);
        cv.bb[3] = __float2bfloat16(v.w);
        *(ushort4*)(x_bf + 4l * i) = cv.u;
    } else if (b < PRE_CONV + PRE_ZERO) {
        int i = (b - PRE_CONV) * 256 + tid;
        if (i < 4 * NN) deg4[i] = 0;
    } else {
        int vk = b - PRE_CONV - PRE_ZERO;
        int v = vk >> 3, kg = vk & 7;
        int rel = v & 3;
        const float* Wp = rel == 0 ? W0 : rel == 1 ? W1 : rel == 2 ? W2 : W3;
        const float* vec;
        if (v < 4) vec = rel == 0 ? al0 : rel == 1 ? al1 : rel == 2 ? al2 : al3;
        else vec = rel == 0 ? ar0 : rel == 1 ? ar1 : rel == 2 ? ar2 : ar3;
        int wave = tid >> 6, lane = tid & 63;
#pragma unroll 1
        for (int i = 0; i < 16; i++) {
            int k = kg * 64 + wave * 16 + i;
            float s = 0.f;
#pragma unroll
            for (int c = 0; c < 8; c++) s += Wp[(size_t)k * 512 + c * 64 + lane] * vec[c * 64 + lane];
#pragma unroll
            for (int off = 32; off > 0; off >>= 1) s += __shfl_xor(s, off);
            if (lane == 0) wal8[v * 512 + k] = s;
        }
    }
}

// ---------------- 6x 512x512 transpose + convert to bf16, one launch ----------------
__global__ __launch_bounds__(1024)
void k_transpose6(const float* __restrict__ W0, const float* __restrict__ W1,
                  const float* __restrict__ W2, const float* __restrict__ W3,
                  const float* __restrict__ Wl, __hip_bfloat16* __restrict__ Bt_all,
                  __hip_bfloat16* __restrict__ WlTb) {
    __shared__ float tile[32][33];
    int z = blockIdx.z;
    const float* in = z == 0 ? W0 : z == 1 ? W1 : z == 2 ? W2 : z == 3 ? W3
                      : (z == 4 ? Wl : Wl + (size_t)DD * DD);
    __hip_bfloat16* out = z < 5 ? Bt_all + (size_t)z * DD * DD : WlTb;
    int bx = blockIdx.x * 32;
    int by = blockIdx.y * 32;
    int tx = threadIdx.x, ty = threadIdx.y;
    tile[ty][tx] = in[(by + ty) * 512 + bx + tx];
    __syncthreads();
    out[(bx + ty) * 512 + by + tx] = __float2bfloat16(tile[tx][ty]);
}

// ---------------- el/er for all 4 relations from x: el=x@wal, er=x@war ----------
// One 20MB pass over x_bf (vs 102MB h_all re-read). wave per row; 8 dots/row.
__global__ __launch_bounds__(256)
void k_elr8(const __hip_bfloat16* __restrict__ x_bf, const float* __restrict__ wal8,
            float* __restrict__ el4, float* __restrict__ er4) {
    int wave = threadIdx.x >> 6, lane = threadIdx.x & 63;
    int r = blockIdx.x * 4 + wave;
    uint4 xv = *(const uint4*)(x_bf + (size_t)r * DD + lane * 8);
    const unsigned short* xs = (const unsigned short*)&xv;
    float xf[8];
#pragma unroll
    for (int j = 0; j < 8; j++) xf[j] = bfbits2f(xs[j]);
    float s[8];
#pragma unroll
    for (int v = 0; v < 8; v++) {
        const float* wp = wal8 + v * 512 + lane * 8;
        s[v] = xf[0] * wp[0] + xf[1] * wp[1] + xf[2] * wp[2] + xf[3] * wp[3] +
               xf[4] * wp[4] + xf[5] * wp[5] + xf[6] * wp[6] + xf[7] * wp[7];
    }
#pragma unroll
    for (int off = 32; off > 0; off >>= 1)
#pragma unroll
        for (int v = 0; v < 8; v++) s[v] += __shfl_xor(s[v], off);
    if (lane == 0) {
#pragma unroll
        for (int rel = 0; rel < 4; rel++) {
            el4[rel * NN + r] = s[rel];
            er4[rel * NN + r] = s[4 + rel];
        }
    }
}

// ---------------- MEGA GEMM: 128x128, BK=64, XCD swizzle (R10-proven) ----------
__global__ __launch_bounds__(256)
void k_gemm128(const __hip_bfloat16* __restrict__ A, const __hip_bfloat16* __restrict__ Bt,
               __hip_bfloat16* __restrict__ Cb, int c_ld, int M, int CT) {
    const int RT = (M + 127) >> 7;
    const int xcd = blockIdx.x & 7;
    const int k_ = blockIdx.x >> 3;
    const int ctile = k_ % CT;
    const int rtile = (k_ / CT) * 8 + xcd;
    if (rtile >= RT) return;

    __shared__ __hip_bfloat16 As[128 * 64];
    __shared__ __hip_bfloat16 Bs[128 * 64];
    const int tid = threadIdx.x;
    const int lane = tid & 63;
    const int wave = tid >> 6;
    const int row0 = rtile * 128;
    const int col0 = ctile * 128;
    const int wm = (wave >> 1) * 64;
    const int wn = (wave & 1) * 64;
    const int q8 = lane >> 4;
    const int l15 = lane & 15;

    int ar_ = row0 + (tid & 127);
    if (ar_ >= M) ar_ = M - 1;
    const __hip_bfloat16* aptr = A + (size_t)ar_ * DD + (tid >> 7) * 8;
    const __hip_bfloat16* bptr = Bt + (size_t)(col0 + (tid & 127)) * DD + (tid >> 7) * 8;
    __hip_bfloat16* alds = As + (size_t)tid * 8;
    __hip_bfloat16* blds = Bs + (size_t)tid * 8;

    floatx4 acc[4][4];
#pragma unroll
    for (int a = 0; a < 4; a++)
#pragma unroll
        for (int b = 0; b < 4; b++) acc[a][b] = (floatx4){0.f, 0.f, 0.f, 0.f};

    for (int k0 = 0; k0 < DD; k0 += 64) {
        __syncthreads();
#pragma unroll
        for (int j = 0; j < 4; j++) {
            GLOAD_LDS16(aptr + k0 + j * 16, alds + (size_t)j * 256 * 8);
            GLOAD_LDS16(bptr + k0 + j * 16, blds + (size_t)j * 256 * 8);
        }
        __syncthreads();
#pragma unroll
        for (int kk = 0; kk < 2; kk++) {
            short8 af[4], bf[4];
#pragma unroll
            for (int mi = 0; mi < 4; mi++)
                af[mi] =
                    *(const short8*)(As + ((size_t)(kk * 4 + q8) * 128 + wm + mi * 16 + l15) * 8);
#pragma unroll
            for (int ni = 0; ni < 4; ni++)
                bf[ni] =
                    *(const short8*)(Bs + ((size_t)(kk * 4 + q8) * 128 + wn + ni * 16 + l15) * 8);
#pragma unroll
            for (int mi = 0; mi < 4; mi++)
#pragma unroll
                for (int ni = 0; ni < 4; ni++)
                    acc[mi][ni] = __builtin_amdgcn_mfma_f32_16x16x32_bf16(af[mi], bf[ni],
                                                                          acc[mi][ni], 0, 0, 0);
        }
    }

#pragma unroll
    for (int mi = 0; mi < 4; mi++)
#pragma unroll
        for (int ni = 0; ni < 4; ni++)
#pragma unroll
            for (int r = 0; r < 4; r++) {
                int grow = row0 + wm + mi * 16 + q8 * 4 + r;
                int gcol = col0 + wn + ni * 16 + l15;
                if (grow < M) Cb[(size_t)grow * c_ld + gcol] = __float2bfloat16(acc[mi][ni][r]);
            }
}

// ---------------- CHAIN GEMM with fused t-propagation (R10-proven) ----------------
__global__ __launch_bounds__(256)
void k_chain(const __hip_bfloat16* __restrict__ A, const __hip_bfloat16* __restrict__ Bt,
             const __hip_bfloat16* __restrict__ xwl, const __hip_bfloat16* __restrict__ gnext,
             __hip_bfloat16* __restrict__ t_next, float* __restrict__ outf, int M) {
    const int CT = 4;
    const int RT = (M + 63) >> 6;
    const int xcd = blockIdx.x & 7;
    const int k_ = blockIdx.x >> 3;
    const int ctile = k_ % CT;
    const int rtile = (k_ / CT) * 8 + xcd;
    if (rtile >= RT) return;

    __shared__ __hip_bfloat16 As[64 * 64];
    __shared__ __hip_bfloat16 Bs[128 * 64];
    const int tid = threadIdx.x;
    const int lane = tid & 63;
    const int wave = tid >> 6;
    const int row0 = rtile * 64;
    const int col0 = ctile * 128;
    const int wm = (wave >> 1) * 32;
    const int wn = (wave & 1) * 64;
    const int q8 = lane >> 4;
    const int l15 = lane & 15;

    int ar_ = row0 + (tid & 63);
    if (ar_ >= M) ar_ = M - 1;
    const __hip_bfloat16* aptr = A + (size_t)ar_ * DD + (tid >> 6) * 8;
    __hip_bfloat16* alds = As + (size_t)tid * 8;
    const __hip_bfloat16* bptr = Bt + (size_t)(col0 + (tid & 127)) * DD + (tid >> 7) * 8;
    __hip_bfloat16* blds = Bs + (size_t)tid * 8;

    floatx4 acc[2][4];
#pragma unroll
    for (int a = 0; a < 2; a++)
#pragma unroll
        for (int b = 0; b < 4; b++) acc[a][b] = (floatx4){0.f, 0.f, 0.f, 0.f};

    for (int k0 = 0; k0 < DD; k0 += 64) {
        __syncthreads();
        GLOAD_LDS16(aptr + k0, alds);
        GLOAD_LDS16(aptr + k0 + 32, alds + 256 * 8);
#pragma unroll
        for (int j = 0; j < 4; j++)
            GLOAD_LDS16(bptr + k0 + j * 16, blds + (size_t)j * 256 * 8);
        __syncthreads();
#pragma unroll
        for (int kk = 0; kk < 2; kk++) {
            short8 af[2], bf[4];
#pragma unroll
            for (int mi = 0; mi < 2; mi++)
                af[mi] =
                    *(const short8*)(As + ((size_t)(kk * 4 + q8) * 64 + wm + mi * 16 + l15) * 8);
#pragma unroll
            for (int ni = 0; ni < 4; ni++)
                bf[ni] =
                    *(const short8*)(Bs + ((size_t)(kk * 4 + q8) * 128 + wn + ni * 16 + l15) * 8);
#pragma unroll
            for (int mi = 0; mi < 2; mi++)
#pragma unroll
                for (int ni = 0; ni < 4; ni++)
                    acc[mi][ni] = __builtin_amdgcn_mfma_f32_16x16x32_bf16(af[mi], bf[ni],
                                                                          acc[mi][ni], 0, 0, 0);
        }
    }

#pragma unroll
    for (int mi = 0; mi < 2; mi++)
#pragma unroll
        for (int ni = 0; ni < 4; ni++)
#pragma unroll
            for (int r = 0; r < 4; r++) {
                int grow = row0 + wm + mi * 16 + q8 * 4 + r;
                int gcol = col0 + wn + ni * 16 + l15;
                if (grow < M) {
                    float v = acc[mi][ni][r];
                    v += bfbits2f(*(const unsigned short*)(xwl + (size_t)grow * NH + 2048 + gcol));
                    v = v > 0.f ? v : 0.f;  // v = out_i
                    size_t idx = (size_t)grow * DD + gcol;
                    if (t_next) {
                        v += bfbits2f(*(const unsigned short*)(gnext + idx));
                        t_next[idx] = __float2bfloat16(v);
                    } else {
                        outf[idx] = v;
                    }
                }
            }
}

// ---------------- CSR build (batched over 4 relations) ----------------
__global__ void k_count4(const int* __restrict__ e0, const int* __restrict__ e1,
                         const int* __restrict__ e2, const int* __restrict__ e3,
                         int* __restrict__ deg4) {
    int g = blockIdx.x * blockDim.x + threadIdx.x;
    if (g >= 4 * EE) return;
    int rel = g / EE;
    int e = g - rel * EE;
    const int* ed = rel == 0 ? e0 : rel == 1 ? e1 : rel == 2 ? e2 : e3;
    atomicAdd(&deg4[rel * NN + ed[EE + e]], 1);
}

__global__ __launch_bounds__(1024)
void k_scan4(const int* __restrict__ deg4, int* __restrict__ rp4, int* __restrict__ cur4) {
    const int rel = blockIdx.x;
    const int* deg = deg4 + rel * NN;
    int* row_ptr = rp4 + rel * (NN + 1);
    int* cursor = cur4 + rel * NN;
    __shared__ int sm[1024];
    int t = threadIdx.x;
    const int CH = 20;
    int begin = t * CH;
    int end = begin + CH;
    if (end > NN) end = NN;
    int s = 0;
    if (begin < NN)
        for (int i = begin; i < end; i++) s += deg[i];
    sm[t] = s;
    __syncthreads();
    for (int off = 1; off < 1024; off <<= 1) {
        int v = (t >= off) ? sm[t - off] : 0;
        __syncthreads();
        sm[t] += v;
        __syncthreads();
    }
    int run = sm[t] - s;
    if (begin < NN) {
        for (int i = begin; i < end; i++) {
            row_ptr[i] = run;
            cursor[i] = run;
            run += deg[i];
        }
        if (end == NN) row_ptr[NN] = run;
    }
}

__global__ void k_scatter4(const int* __restrict__ e0, const int* __restrict__ e1,
                           const int* __restrict__ e2, const int* __restrict__ e3,
                           int* __restrict__ cur4, int* __restrict__ csr4) {
    int g = blockIdx.x * blockDim.x + threadIdx.x;
    if (g >= 4 * EE) return;
    int rel = g / EE;
    int e = g - rel * EE;
    const int* ed = rel == 0 ? e0 : rel == 1 ? e1 : rel == 2 ? e2 : e3;
    int dst = ed[EE + e];
    int pos = atomicAdd(&cur4[rel * NN + dst], 1);
    csr4[rel * EE + pos] = ed[e];
}

// ---------------- BATCHED edge-softmax + aggregate (+bias), wave per dst ----------
__global__ __launch_bounds__(256)
void k_agg4(const int* __restrict__ rp4, const int* __restrict__ csr4,
            const float* __restrict__ el4, const float* __restrict__ er4,
            const __hip_bfloat16* __restrict__ h_all, const float* __restrict__ bias,
            __hip_bfloat16* __restrict__ gat4, float* __restrict__ alpha4) {
    const int rel = blockIdx.y;
    const int* row_ptr = rp4 + rel * (NN + 1);
    const int* csr_src = csr4 + (size_t)rel * EE;
    const float* el = el4 + rel * NN;
    const float* er = er4 + rel * NN;
    const __hip_bfloat16* h = h_all + (size_t)rel * 512;
    float* alpha_tmp = alpha4 + (size_t)rel * EE;

    int d = (blockIdx.x * blockDim.x + threadIdx.x) >> 6;
    int lane = threadIdx.x & 63;
    if (d >= NN) return;
    int s0 = row_ptr[d], s1 = row_ptr[d + 1];
    int deg = s1 - s0;
    int base = lane * 8;
    float acc[8] = {0.f, 0.f, 0.f, 0.f, 0.f, 0.f, 0.f, 0.f};

    if (deg <= 64) {
        int sv = 0;
        float av = 0.f;
        if (lane < deg) sv = csr_src[s0 + lane];
        float erd = er[d];
        float v = -1e30f;
        if (lane < deg) {
            float e = el[sv] + erd;
            v = e >= 0.f ? e : 0.2f * e;
        }
        float m = v;
#pragma unroll
        for (int off = 32; off > 0; off >>= 1) m = fmaxf(m, __shfl_xor(m, off));
        float wgt = (lane < deg) ? __expf(v - m) : 0.f;
        float s = wgt;
#pragma unroll
        for (int off = 32; off > 0; off >>= 1) s += __shfl_xor(s, off);
        av = wgt / s;
        int t = 0;
        for (; t + 3 < deg; t += 4) {
            int sA = __shfl(sv, t), sB = __shfl(sv, t + 1);
            int sC = __shfl(sv, t + 2), sD = __shfl(sv, t + 3);
            float aA = __shfl(av, t), aB = __shfl(av, t + 1);
            float aC = __shfl(av, t + 2), aD = __shfl(av, t + 3);
            uint4 hv0 = *(const uint4*)(h + (size_t)sA * NH + base);
            uint4 hv1 = *(const uint4*)(h + (size_t)sB * NH + base);
            uint4 hv2 = *(const uint4*)(h + (size_t)sC * NH + base);
            uint4 hv3 = *(const uint4*)(h + (size_t)sD * NH + base);
            const unsigned short* h0 = (const unsigned short*)&hv0;
            const unsigned short* h1 = (const unsigned short*)&hv1;
            const unsigned short* h2 = (const unsigned short*)&hv2;
            const unsigned short* h3 = (const unsigned short*)&hv3;
#pragma unroll
            for (int k = 0; k < 8; k++)
                acc[k] += aA * bfbits2f(h0[k]) + aB * bfbits2f(h1[k]) + aC * bfbits2f(h2[k]) +
                          aD * bfbits2f(h3[k]);
        }
        for (; t < deg; t++) {
            int sA = __shfl(sv, t);
            float aA = __shfl(av, t);
            uint4 hv0 = *(const uint4*)(h + (size_t)sA * NH + base);
            const unsigned short* h0 = (const unsigned short*)&hv0;
#pragma unroll
            for (int k = 0; k < 8; k++) acc[k] += aA * bfbits2f(h0[k]);
        }
    } else {
        float erd = er[d];
        float m = -1e30f;
        for (int j = s0 + lane; j < s1; j += 64) {
            float e = el[csr_src[j]] + erd;
            e = e >= 0.f ? e : 0.2f * e;
            alpha_tmp[j] = e;
            m = fmaxf(m, e);
        }
#pragma unroll
        for (int off = 32; off > 0; off >>= 1) m = fmaxf(m, __shfl_xor(m, off));
        float s = 0.f;
        for (int j = s0 + lane; j < s1; j += 64) {
            float wv = __expf(alpha_tmp[j] - m);
            alpha_tmp[j] = wv;
            s += wv;
        }
#pragma unroll
        for (int off = 32; off > 0; off >>= 1) s += __shfl_xor(s, off);
        float inv = 1.f / s;
        for (int j0 = 0; j0 < deg; j0 += 64) {
            int cnt = deg - j0;
            if (cnt > 64) cnt = 64;
            int sv = 0;
            float av = 0.f;
            if (lane < cnt) {
                sv = csr_src[s0 + j0 + lane];
                av = alpha_tmp[s0 + j0 + lane] * inv;
            }
            for (int t = 0; t < cnt; t++) {
                int sA = __shfl(sv, t);
                float aA = __shfl(av, t);
                uint4 hv0 = *(const uint4*)(h + (size_t)sA * NH + base);
                const unsigned short* h0 = (const unsigned short*)&hv0;
#pragma unroll
                for (int k = 0; k < 8; k++) acc[k] += aA * bfbits2f(h0[k]);
            }
        }
    }

    float4 b0 = *(const float4*)(bias + base);
    float4 b1 = *(const float4*)(bias + base + 4);
    acc[0] += b0.x; acc[1] += b0.y; acc[2] += b0.z; acc[3] += b0.w;
    acc[4] += b1.x; acc[5] += b1.y; acc[6] += b1.z; acc[7] += b1.w;
    union { __hip_bfloat16 b[8]; uint4 u; } cv;
#pragma unroll
    for (int k = 0; k < 8; k++) cv.b[k] = __float2bfloat16(acc[k]);
    *(uint4*)(gat4 + (size_t)rel * NN * DD + (size_t)d * DD + base) = cv.u;
}

extern "C" void kernel_launch(void* const* d_in, const int* in_sizes, int n_in,
                              void* d_out, int out_size, void* d_ws, size_t ws_size,
                              hipStream_t stream) {
    const float* x = (const float*)d_in[0];
    const int* edges[4] = {(const int*)d_in[1], (const int*)d_in[5], (const int*)d_in[9],
                           (const int*)d_in[13]};
    const float* W[4] = {(const float*)d_in[2], (const float*)d_in[6], (const float*)d_in[10],
                         (const float*)d_in[14]};
    const float* al[4] = {(const float*)d_in[3], (const float*)d_in[7], (const float*)d_in[11],
                          (const float*)d_in[15]};
    const float* ar[4] = {(const float*)d_in[4], (const float*)d_in[8], (const float*)d_in[12],
                          (const float*)d_in[16]};
    const float* Wl = (const float*)d_in[17];
    const float* bias = (const float*)d_in[18];
    float* out = (float*)d_out;

    char* w = (char*)d_ws;
    auto alloc = [&](size_t bytes) {
        char* p = w;
        w += (bytes + 255) & ~(size_t)255;
        return p;
    };
    __hip_bfloat16* x_bf = (__hip_bfloat16*)alloc((size_t)NN * DD * 2);
    __hip_bfloat16* h_all = (__hip_bfloat16*)alloc((size_t)NN * NH * 2);   // [h0..h3|xwl]
    __hip_bfloat16* gat4 = (__hip_bfloat16*)alloc((size_t)4 * NN * DD * 2);
    __hip_bfloat16* t_A = (__hip_bfloat16*)alloc((size_t)NN * DD * 2);
    __hip_bfloat16* t_B = (__hip_bfloat16*)alloc((size_t)NN * DD * 2);
    __hip_bfloat16* Bt_all = (__hip_bfloat16*)alloc((size_t)NH * DD * 2);  // [W0..W3,WlTop]^T
    __hip_bfloat16* WlTb = (__hip_bfloat16*)alloc((size_t)DD * DD * 2);
    float* wal8 = (float*)alloc((size_t)8 * 512 * 4);
    float* el4 = (float*)alloc((size_t)4 * NN * 4);
    float* er4 = (float*)alloc((size_t)4 * NN * 4);
    int* deg4 = (int*)alloc((size_t)4 * NN * 4);
    int* rp4 = (int*)alloc((size_t)4 * (NN + 1) * 4);
    int* cur4 = (int*)alloc((size_t)4 * NN * 4);
    int* csr4 = (int*)alloc((size_t)4 * EE * 4);
    float* alpha4 = (float*)alloc((size_t)4 * EE * 4);

    // fused preprocessing: convert x, zero deg4, wal8 = W@al / W@ar
    k_preproc<<<PRE_CONV + PRE_ZERO + PRE_WAL, 256, 0, stream>>>(
        x, x_bf, deg4, W[0], W[1], W[2], W[3], al[0], al[1], al[2], al[3], ar[0], ar[1], ar[2],
        ar[3], wal8);
    dim3 tb(32, 32), tg6(16, 16, 6);
    k_transpose6<<<tg6, tb, 0, stream>>>(W[0], W[1], W[2], W[3], Wl, Bt_all, WlTb);

    // CSR for all 4 relations
    k_count4<<<(4 * EE + 255) / 256, 256, 0, stream>>>(edges[0], edges[1], edges[2], edges[3], deg4);
    k_scan4<<<4, 1024, 0, stream>>>(deg4, rp4, cur4);
    k_scatter4<<<(4 * EE + 255) / 256, 256, 0, stream>>>(edges[0], edges[1], edges[2], edges[3],
                                                         cur4, csr4);

    // el/er from x directly (20MB pass instead of 102MB h_all re-read)
    k_elr8<<<NN / 4, 256, 0, stream>>>(x_bf, wal8, el4, er4);

    // MEGA-GEMM: h_all = x @ [W0..W3|Wl_top], 128x128 tiles, CT=20
    const int RT128p8 = (((NN + 127) / 128 + 7) / 8) * 8;  // 160
    k_gemm128<<<RT128p8 * 20, 256, 0, stream>>>(x_bf, Bt_all, h_all, NH, NN, 20);

    // batched aggregate (+bias), wave per dst
    dim3 gagg((NN * 64 + 255) / 256, 4);
    k_agg4<<<gagg, 256, 0, stream>>>(rp4, csr4, el4, er4, h_all, bias, gat4, alpha4);

    // serial chain: t_{i+1} = relu(t_i @ Wl_bot + xwl) + gat4[i+1]; last writes fp32 out
    const int RT64p8 = (((NN + 63) / 64 + 7) / 8) * 8;  // 320
    const int NB = RT64p8 * 4;
    k_chain<<<NB, 256, 0, stream>>>(gat4, WlTb, h_all, gat4 + (size_t)1 * NN * DD, t_A, nullptr,
                                    NN);
    k_chain<<<NB, 256, 0, stream>>>(t_A, WlTb, h_all, gat4 + (size_t)2 * NN * DD, t_B, nullptr,
                                    NN);
    k_chain<<<NB, 256, 0, stream>>>(t_B, WlTb, h_all, gat4 + (size_t)3 * NN * DD, t_A, nullptr,
                                    NN);
    k_chain<<<NB, 256, 0, stream>>>(t_A, WlTb, h_all, nullptr, nullptr, out, NN);
}

// Round 13
// 633.789 us; speedup vs baseline: 1.0851x; 1.0428x over previous
//
#include <hip/hip_runtime.h>
#include <hip/hip_bf16.h>

#define NN 20000
#define DD 512
#define EE 150000
#define NH 2560  // stacked GEMM width: 4*512 (W_i) + 512 (Wl_top)

typedef __attribute__((ext_vector_type(8))) short short8;
typedef __attribute__((ext_vector_type(4))) float floatx4;

static __device__ __forceinline__ float bfbits2f(unsigned short u) {
    unsigned int x = ((unsigned int)u) << 16;
    return __uint_as_float(x);
}

#define GLOAD_LDS16(g, l)                                                        \
    __builtin_amdgcn_global_load_lds((const __attribute__((address_space(1))) void*)(g), \
                                     (__attribute__((address_space(3))) void*)(l), 16, 0, 0)

// ---------------- fused preprocessing: convert x, zero deg4, wal8 ----------------
#define PRE_CONV 10000
#define PRE_ZERO 313
#define PRE_WAL 64
__global__ __launch_bounds__(256)
void k_preproc(const float* __restrict__ x, __hip_bfloat16* __restrict__ x_bf,
               int* __restrict__ deg4,
               const float* __restrict__ W0, const float* __restrict__ W1,
               const float* __restrict__ W2, const float* __restrict__ W3,
               const float* __restrict__ al0, const float* __restrict__ al1,
               const float* __restrict__ al2, const float* __restrict__ al3,
               const float* __restrict__ ar0, const float* __restrict__ ar1,
               const float* __restrict__ ar2, const float* __restrict__ ar3,
               float* __restrict__ wal8) {
    int b = blockIdx.x;
    int tid = threadIdx.x;
    if (b < PRE_CONV) {
        int i = b * 256 + tid;
        float4 v = ((const float4*)x)[i];
        union { __hip_bfloat16 bb[4]; ushort4 u; } cv;
        cv.bb[0] = __float2bfloat16(v.x);
        cv.bb[1] = __float2bfloat16(v.y);
        cv.bb[2] = __float2bfloat16(v.z);
        cv.bb[3] = __float2bfloat16(v.w);
        *(ushort4*)(x_bf + 4l * i) = cv.u;
    } else if (b < PRE_CONV + PRE_ZERO) {
        int i = (b - PRE_CONV) * 256 + tid;
        if (i < 4 * NN) deg4[i] = 0;
    } else {
        int vk = b - PRE_CONV - PRE_ZERO;
        int v = vk >> 3, kg = vk & 7;
        int rel = v & 3;
        const float* Wp = rel == 0 ? W0 : rel == 1 ? W1 : rel == 2 ? W2 : W3;
        const float* vec;
        if (v < 4) vec = rel == 0 ? al0 : rel == 1 ? al1 : rel == 2 ? al2 : al3;
        else vec = rel == 0 ? ar0 : rel == 1 ? ar1 : rel == 2 ? ar2 : ar3;
        int wave = tid >> 6, lane = tid & 63;
#pragma unroll 1
        for (int i = 0; i < 16; i++) {
            int k = kg * 64 + wave * 16 + i;
            float s = 0.f;
#pragma unroll
            for (int c = 0; c < 8; c++) s += Wp[(size_t)k * 512 + c * 64 + lane] * vec[c * 64 + lane];
#pragma unroll
            for (int off = 32; off > 0; off >>= 1) s += __shfl_xor(s, off);
            if (lane == 0) wal8[v * 512 + k] = s;
        }
    }
}

// ---------------- 6x 512x512 transpose + convert to bf16, one launch ----------------
__global__ __launch_bounds__(1024)
void k_transpose6(const float* __restrict__ W0, const float* __restrict__ W1,
                  const float* __restrict__ W2, const float* __restrict__ W3,
                  const float* __restrict__ Wl, __hip_bfloat16* __restrict__ Bt_all,
                  __hip_bfloat16* __restrict__ WlTb) {
    __shared__ float tile[32][33];
    int z = blockIdx.z;
    const float* in = z == 0 ? W0 : z == 1 ? W1 : z == 2 ? W2 : z == 3 ? W3
                      : (z == 4 ? Wl : Wl + (size_t)DD * DD);
    __hip_bfloat16* out = z < 5 ? Bt_all + (size_t)z * DD * DD : WlTb;
    int bx = blockIdx.x * 32;
    int by = blockIdx.y * 32;
    int tx = threadIdx.x, ty = threadIdx.y;
    tile[ty][tx] = in[(by + ty) * 512 + bx + tx];
    __syncthreads();
    out[(bx + ty) * 512 + by + tx] = __float2bfloat16(tile[tx][ty]);
}

// ---------------- el/er for all 4 relations from x (wal8 algebra) ----------------
__global__ __launch_bounds__(256)
void k_elr8(const __hip_bfloat16* __restrict__ x_bf, const float* __restrict__ wal8,
            float* __restrict__ el4, float* __restrict__ er4) {
    int wave = threadIdx.x >> 6, lane = threadIdx.x & 63;
    int r = blockIdx.x * 4 + wave;
    uint4 xv = *(const uint4*)(x_bf + (size_t)r * DD + lane * 8);
    const unsigned short* xs = (const unsigned short*)&xv;
    float xf[8];
#pragma unroll
    for (int j = 0; j < 8; j++) xf[j] = bfbits2f(xs[j]);
    float s[8];
#pragma unroll
    for (int v = 0; v < 8; v++) {
        const float* wp = wal8 + v * 512 + lane * 8;
        s[v] = xf[0] * wp[0] + xf[1] * wp[1] + xf[2] * wp[2] + xf[3] * wp[3] +
               xf[4] * wp[4] + xf[5] * wp[5] + xf[6] * wp[6] + xf[7] * wp[7];
    }
#pragma unroll
    for (int off = 32; off > 0; off >>= 1)
#pragma unroll
        for (int v = 0; v < 8; v++) s[v] += __shfl_xor(s[v], off);
    if (lane == 0) {
#pragma unroll
        for (int rel = 0; rel < 4; rel++) {
            el4[rel * NN + r] = s[rel];
            er4[rel * NN + r] = s[4 + rel];
        }
    }
}

// ---------------- GEMM: 128x128 tile, BK=64, XCD swizzle, 512 threads / 8 waves ----
// R12 showed Occupancy 20% (152 unified regs/wave with acc[4][4]) was the
// latency-hiding bottleneck. 8 waves of 64x32 each: acc = 8 floatx4 = 32 AGPR
// -> ~2x waves/CU. Same LDS (32KB), same staging bytes, same swizzle.
// mode 0: Cb[grow*c_ld+gcol] = bf16(C)   (mega)
// mode 1: t_next = bf16(relu(C + xwl) + gnext)   (chain mid)
// mode 2: outf = relu(C + xwl) fp32              (chain last)
__global__ __launch_bounds__(512)
void k_gemm512(const __hip_bfloat16* __restrict__ A, const __hip_bfloat16* __restrict__ Bt,
               __hip_bfloat16* __restrict__ Cb, const __hip_bfloat16* __restrict__ xwl,
               const __hip_bfloat16* __restrict__ gnext, __hip_bfloat16* __restrict__ t_next,
               float* __restrict__ outf, int c_ld, int M, int CT, int mode) {
    const int RT = (M + 127) >> 7;
    const int xcd = blockIdx.x & 7;
    const int k_ = blockIdx.x >> 3;
    const int ctile = k_ % CT;
    const int rtile = (k_ / CT) * 8 + xcd;
    if (rtile >= RT) return;

    __shared__ __hip_bfloat16 As[128 * 64];  // 16 KB; 16B-block b = [q=b>>7][r=b&127]
    __shared__ __hip_bfloat16 Bs[128 * 64];  // 16 KB
    const int tid = threadIdx.x;
    const int lane = tid & 63;
    const int wave = tid >> 6;
    const int row0 = rtile * 128;
    const int col0 = ctile * 128;
    const int wm = (wave >> 2) * 64;   // 0 or 64
    const int wn = (wave & 3) * 32;    // 0,32,64,96
    const int q8 = lane >> 4;
    const int l15 = lane & 15;

    int ar_ = row0 + (tid & 127);
    if (ar_ >= M) ar_ = M - 1;
    const __hip_bfloat16* aptr = A + (size_t)ar_ * DD + (tid >> 7) * 8;  // q = tid>>7 (0..3)
    const __hip_bfloat16* bptr = Bt + (size_t)(col0 + (tid & 127)) * DD + (tid >> 7) * 8;
    __hip_bfloat16* alds = As + (size_t)tid * 8;
    __hip_bfloat16* blds = Bs + (size_t)tid * 8;

    floatx4 acc[4][2];
#pragma unroll
    for (int a = 0; a < 4; a++)
#pragma unroll
        for (int b = 0; b < 2; b++) acc[a][b] = (floatx4){0.f, 0.f, 0.f, 0.f};

    for (int k0 = 0; k0 < DD; k0 += 64) {
        __syncthreads();
        GLOAD_LDS16(aptr + k0, alds);                    // q = tid>>7
        GLOAD_LDS16(aptr + k0 + 32, alds + 512 * 8);     // q = (tid>>7)+4
        GLOAD_LDS16(bptr + k0, blds);
        GLOAD_LDS16(bptr + k0 + 32, blds + 512 * 8);
        __syncthreads();
#pragma unroll
        for (int kk = 0; kk < 2; kk++) {
            short8 af[4], bf[2];
#pragma unroll
            for (int mi = 0; mi < 4; mi++)
                af[mi] =
                    *(const short8*)(As + ((size_t)(kk * 4 + q8) * 128 + wm + mi * 16 + l15) * 8);
#pragma unroll
            for (int ni = 0; ni < 2; ni++)
                bf[ni] =
                    *(const short8*)(Bs + ((size_t)(kk * 4 + q8) * 128 + wn + ni * 16 + l15) * 8);
#pragma unroll
            for (int mi = 0; mi < 4; mi++)
#pragma unroll
                for (int ni = 0; ni < 2; ni++)
                    acc[mi][ni] = __builtin_amdgcn_mfma_f32_16x16x32_bf16(af[mi], bf[ni],
                                                                          acc[mi][ni], 0, 0, 0);
        }
    }

#pragma unroll
    for (int mi = 0; mi < 4; mi++)
#pragma unroll
        for (int ni = 0; ni < 2; ni++)
#pragma unroll
            for (int r = 0; r < 4; r++) {
                int grow = row0 + wm + mi * 16 + q8 * 4 + r;
                int gcol = col0 + wn + ni * 16 + l15;
                if (grow < M) {
                    float v = acc[mi][ni][r];
                    if (mode == 0) {
                        Cb[(size_t)grow * c_ld + gcol] = __float2bfloat16(v);
                    } else {
                        v += bfbits2f(
                            *(const unsigned short*)(xwl + (size_t)grow * NH + 2048 + gcol));
                        v = v > 0.f ? v : 0.f;
                        size_t idx = (size_t)grow * DD + gcol;
                        if (mode == 1) {
                            v += bfbits2f(*(const unsigned short*)(gnext + idx));
                            t_next[idx] = __float2bfloat16(v);
                        } else {
                            outf[idx] = v;
                        }
                    }
                }
            }
}

// ---------------- CSR build (batched over 4 relations) ----------------
__global__ void k_count4(const int* __restrict__ e0, const int* __restrict__ e1,
                         const int* __restrict__ e2, const int* __restrict__ e3,
                         int* __restrict__ deg4) {
    int g = blockIdx.x * blockDim.x + threadIdx.x;
    if (g >= 4 * EE) return;
    int rel = g / EE;
    int e = g - rel * EE;
    const int* ed = rel == 0 ? e0 : rel == 1 ? e1 : rel == 2 ? e2 : e3;
    atomicAdd(&deg4[rel * NN + ed[EE + e]], 1);
}

__global__ __launch_bounds__(1024)
void k_scan4(const int* __restrict__ deg4, int* __restrict__ rp4, int* __restrict__ cur4) {
    const int rel = blockIdx.x;
    const int* deg = deg4 + rel * NN;
    int* row_ptr = rp4 + rel * (NN + 1);
    int* cursor = cur4 + rel * NN;
    __shared__ int sm[1024];
    int t = threadIdx.x;
    const int CH = 20;
    int begin = t * CH;
    int end = begin + CH;
    if (end > NN) end = NN;
    int s = 0;
    if (begin < NN)
        for (int i = begin; i < end; i++) s += deg[i];
    sm[t] = s;
    __syncthreads();
    for (int off = 1; off < 1024; off <<= 1) {
        int v = (t >= off) ? sm[t - off] : 0;
        __syncthreads();
        sm[t] += v;
        __syncthreads();
    }
    int run = sm[t] - s;
    if (begin < NN) {
        for (int i = begin; i < end; i++) {
            row_ptr[i] = run;
            cursor[i] = run;
            run += deg[i];
        }
        if (end == NN) row_ptr[NN] = run;
    }
}

__global__ void k_scatter4(const int* __restrict__ e0, const int* __restrict__ e1,
                           const int* __restrict__ e2, const int* __restrict__ e3,
                           int* __restrict__ cur4, int* __restrict__ csr4) {
    int g = blockIdx.x * blockDim.x + threadIdx.x;
    if (g >= 4 * EE) return;
    int rel = g / EE;
    int e = g - rel * EE;
    const int* ed = rel == 0 ? e0 : rel == 1 ? e1 : rel == 2 ? e2 : e3;
    int dst = ed[EE + e];
    int pos = atomicAdd(&cur4[rel * NN + dst], 1);
    csr4[rel * EE + pos] = ed[e];
}

// ---------------- BATCHED edge-softmax + aggregate (+bias), wave per dst ----------
__global__ __launch_bounds__(256)
void k_agg4(const int* __restrict__ rp4, const int* __restrict__ csr4,
            const float* __restrict__ el4, const float* __restrict__ er4,
            const __hip_bfloat16* __restrict__ h_all, const float* __restrict__ bias,
            __hip_bfloat16* __restrict__ gat4, float* __restrict__ alpha4) {
    const int rel = blockIdx.y;
    const int* row_ptr = rp4 + rel * (NN + 1);
    const int* csr_src = csr4 + (size_t)rel * EE;
    const float* el = el4 + rel * NN;
    const float* er = er4 + rel * NN;
    const __hip_bfloat16* h = h_all + (size_t)rel * 512;
    float* alpha_tmp = alpha4 + (size_t)rel * EE;

    int d = (blockIdx.x * blockDim.x + threadIdx.x) >> 6;
    int lane = threadIdx.x & 63;
    if (d >= NN) return;
    int s0 = row_ptr[d], s1 = row_ptr[d + 1];
    int deg = s1 - s0;
    int base = lane * 8;
    float acc[8] = {0.f, 0.f, 0.f, 0.f, 0.f, 0.f, 0.f, 0.f};

    if (deg <= 64) {
        int sv = 0;
        float av = 0.f;
        if (lane < deg) sv = csr_src[s0 + lane];
        float erd = er[d];
        float v = -1e30f;
        if (lane < deg) {
            float e = el[sv] + erd;
            v = e >= 0.f ? e : 0.2f * e;
        }
        float m = v;
#pragma unroll
        for (int off = 32; off > 0; off >>= 1) m = fmaxf(m, __shfl_xor(m, off));
        float wgt = (lane < deg) ? __expf(v - m) : 0.f;
        float s = wgt;
#pragma unroll
        for (int off = 32; off > 0; off >>= 1) s += __shfl_xor(s, off);
        av = wgt / s;
        int t = 0;
        for (; t + 3 < deg; t += 4) {
            int sA = __shfl(sv, t), sB = __shfl(sv, t + 1);
            int sC = __shfl(sv, t + 2), sD = __shfl(sv, t + 3);
            float aA = __shfl(av, t), aB = __shfl(av, t + 1);
            float aC = __shfl(av, t + 2), aD = __shfl(av, t + 3);
            uint4 hv0 = *(const uint4*)(h + (size_t)sA * NH + base);
            uint4 hv1 = *(const uint4*)(h + (size_t)sB * NH + base);
            uint4 hv2 = *(const uint4*)(h + (size_t)sC * NH + base);
            uint4 hv3 = *(const uint4*)(h + (size_t)sD * NH + base);
            const unsigned short* h0 = (const unsigned short*)&hv0;
            const unsigned short* h1 = (const unsigned short*)&hv1;
            const unsigned short* h2 = (const unsigned short*)&hv2;
            const unsigned short* h3 = (const unsigned short*)&hv3;
#pragma unroll
            for (int k = 0; k < 8; k++)
                acc[k] += aA * bfbits2f(h0[k]) + aB * bfbits2f(h1[k]) + aC * bfbits2f(h2[k]) +
                          aD * bfbits2f(h3[k]);
        }
        for (; t < deg; t++) {
            int sA = __shfl(sv, t);
            float aA = __shfl(av, t);
            uint4 hv0 = *(const uint4*)(h + (size_t)sA * NH + base);
            const unsigned short* h0 = (const unsigned short*)&hv0;
#pragma unroll
            for (int k = 0; k < 8; k++) acc[k] += aA * bfbits2f(h0[k]);
        }
    } else {
        float erd = er[d];
        float m = -1e30f;
        for (int j = s0 + lane; j < s1; j += 64) {
            float e = el[csr_src[j]] + erd;
            e = e >= 0.f ? e : 0.2f * e;
            alpha_tmp[j] = e;
            m = fmaxf(m, e);
        }
#pragma unroll
        for (int off = 32; off > 0; off >>= 1) m = fmaxf(m, __shfl_xor(m, off));
        float s = 0.f;
        for (int j = s0 + lane; j < s1; j += 64) {
            float wv = __expf(alpha_tmp[j] - m);
            alpha_tmp[j] = wv;
            s += wv;
        }
#pragma unroll
        for (int off = 32; off > 0; off >>= 1) s += __shfl_xor(s, off);
        float inv = 1.f / s;
        for (int j0 = 0; j0 < deg; j0 += 64) {
            int cnt = deg - j0;
            if (cnt > 64) cnt = 64;
            int sv = 0;
            float av = 0.f;
            if (lane < cnt) {
                sv = csr_src[s0 + j0 + lane];
                av = alpha_tmp[s0 + j0 + lane] * inv;
            }
            for (int t = 0; t < cnt; t++) {
                int sA = __shfl(sv, t);
                float aA = __shfl(av, t);
                uint4 hv0 = *(const uint4*)(h + (size_t)sA * NH + base);
                const unsigned short* h0 = (const unsigned short*)&hv0;
#pragma unroll
                for (int k = 0; k < 8; k++) acc[k] += aA * bfbits2f(h0[k]);
            }
        }
    }

    float4 b0 = *(const float4*)(bias + base);
    float4 b1 = *(const float4*)(bias + base + 4);
    acc[0] += b0.x; acc[1] += b0.y; acc[2] += b0.z; acc[3] += b0.w;
    acc[4] += b1.x; acc[5] += b1.y; acc[6] += b1.z; acc[7] += b1.w;
    union { __hip_bfloat16 b[8]; uint4 u; } cv;
#pragma unroll
    for (int k = 0; k < 8; k++) cv.b[k] = __float2bfloat16(acc[k]);
    *(uint4*)(gat4 + (size_t)rel * NN * DD + (size_t)d * DD + base) = cv.u;
}

extern "C" void kernel_launch(void* const* d_in, const int* in_sizes, int n_in,
                              void* d_out, int out_size, void* d_ws, size_t ws_size,
                              hipStream_t stream) {
    const float* x = (const float*)d_in[0];
    const int* edges[4] = {(const int*)d_in[1], (const int*)d_in[5], (const int*)d_in[9],
                           (const int*)d_in[13]};
    const float* W[4] = {(const float*)d_in[2], (const float*)d_in[6], (const float*)d_in[10],
                         (const float*)d_in[14]};
    const float* al[4] = {(const float*)d_in[3], (const float*)d_in[7], (const float*)d_in[11],
                          (const float*)d_in[15]};
    const float* ar[4] = {(const float*)d_in[4], (const float*)d_in[8], (const float*)d_in[12],
                          (const float*)d_in[16]};
    const float* Wl = (const float*)d_in[17];
    const float* bias = (const float*)d_in[18];
    float* out = (float*)d_out;

    char* w = (char*)d_ws;
    auto alloc = [&](size_t bytes) {
        char* p = w;
        w += (bytes + 255) & ~(size_t)255;
        return p;
    };
    __hip_bfloat16* x_bf = (__hip_bfloat16*)alloc((size_t)NN * DD * 2);
    __hip_bfloat16* h_all = (__hip_bfloat16*)alloc((size_t)NN * NH * 2);   // [h0..h3|xwl]
    __hip_bfloat16* gat4 = (__hip_bfloat16*)alloc((size_t)4 * NN * DD * 2);
    __hip_bfloat16* t_A = (__hip_bfloat16*)alloc((size_t)NN * DD * 2);
    __hip_bfloat16* t_B = (__hip_bfloat16*)alloc((size_t)NN * DD * 2);
    __hip_bfloat16* Bt_all = (__hip_bfloat16*)alloc((size_t)NH * DD * 2);  // [W0..W3,WlTop]^T
    __hip_bfloat16* WlTb = (__hip_bfloat16*)alloc((size_t)DD * DD * 2);
    float* wal8 = (float*)alloc((size_t)8 * 512 * 4);
    float* el4 = (float*)alloc((size_t)4 * NN * 4);
    float* er4 = (float*)alloc((size_t)4 * NN * 4);
    int* deg4 = (int*)alloc((size_t)4 * NN * 4);
    int* rp4 = (int*)alloc((size_t)4 * (NN + 1) * 4);
    int* cur4 = (int*)alloc((size_t)4 * NN * 4);
    int* csr4 = (int*)alloc((size_t)4 * EE * 4);
    float* alpha4 = (float*)alloc((size_t)4 * EE * 4);

    // fused preprocessing: convert x, zero deg4, wal8 = W@al / W@ar
    k_preproc<<<PRE_CONV + PRE_ZERO + PRE_WAL, 256, 0, stream>>>(
        x, x_bf, deg4, W[0], W[1], W[2], W[3], al[0], al[1], al[2], al[3], ar[0], ar[1], ar[2],
        ar[3], wal8);
    dim3 tb(32, 32), tg6(16, 16, 6);
    k_transpose6<<<tg6, tb, 0, stream>>>(W[0], W[1], W[2], W[3], Wl, Bt_all, WlTb);

    // CSR for all 4 relations
    k_count4<<<(4 * EE + 255) / 256, 256, 0, stream>>>(edges[0], edges[1], edges[2], edges[3], deg4);
    k_scan4<<<4, 1024, 0, stream>>>(deg4, rp4, cur4);
    k_scatter4<<<(4 * EE + 255) / 256, 256, 0, stream>>>(edges[0], edges[1], edges[2], edges[3],
                                                         cur4, csr4);

    // el/er from x directly
    k_elr8<<<NN / 4, 256, 0, stream>>>(x_bf, wal8, el4, er4);

    // MEGA-GEMM: h_all = x @ [W0..W3|Wl_top], 512-thread blocks, CT=20
    const int RT128p8 = (((NN + 127) / 128 + 7) / 8) * 8;  // 160
    k_gemm512<<<RT128p8 * 20, 512, 0, stream>>>(x_bf, Bt_all, h_all, nullptr, nullptr, nullptr,
                                                nullptr, NH, NN, 20, 0);

    // batched aggregate (+bias), wave per dst
    dim3 gagg((NN * 64 + 255) / 256, 4);
    k_agg4<<<gagg, 256, 0, stream>>>(rp4, csr4, el4, er4, h_all, bias, gat4, alpha4);

    // serial chain: t_{i+1} = relu(t_i @ Wl_bot + xwl) + gat4[i+1]; last writes fp32 out
    const int NB = RT128p8 * 4;
    k_gemm512<<<NB, 512, 0, stream>>>(gat4, WlTb, nullptr, h_all, gat4 + (size_t)1 * NN * DD, t_A,
                                      nullptr, DD, NN, 4, 1);
    k_gemm512<<<NB, 512, 0, stream>>>(t_A, WlTb, nullptr, h_all, gat4 + (size_t)2 * NN * DD, t_B,
                                      nullptr, DD, NN, 4, 1);
    k_gemm512<<<NB, 512, 0, stream>>>(t_B, WlTb, nullptr, h_all, gat4 + (size_t)3 * NN * DD, t_A,
                                      nullptr, DD, NN, 4, 1);
    k_gemm512<<<NB, 512, 0, stream>>>(t_A, WlTb, nullptr, h_all, nullptr, nullptr, out, DD, NN, 4,
                                      2);
}